// Round 1
// baseline (3388.033 us; speedup 1.0000x reference)
//
#include <hip/hip_runtime.h>
#include <math.h>

// Problem constants
#define BATCH 16384
#define DIM   512
#define ZDIM  1024   // 2*DIM
#define HID   256
#define DT    0.1f

// GEMM tile config
#define TILE_M 64
#define TILE_N 64
#define TILE_K 16

// Epilogue modes
#define MODE_TANH 0  // C = tanh(acc + bias[n])
#define MODE_DA2  1  // C = w3[n] * (1 - tanh(acc + bias[n])^2)
#define MODE_DA1  2  // C = acc * (1 - aux[m][n]^2)      (aux = h1, ld = ldc)
#define MODE_UPD  3  // C[m][n] += coef * acc            (C = zp slice, ldc = 1024)

__global__ __launch_bounds__(256)
void gemm_fused(const float* __restrict__ A, int lda,
                const float* __restrict__ B, int ldb,
                const float* __restrict__ bias,
                const float* __restrict__ aux,
                float* __restrict__ C, int ldc,
                int K, int mode, float coef)
{
    __shared__ float As[TILE_M][TILE_K + 1];
    __shared__ float Bs[TILE_K][TILE_N + 1];

    const int tid = threadIdx.x;
    const int block_row = blockIdx.y * TILE_M;
    const int block_col = blockIdx.x * TILE_N;

    const int tx = tid & 15;   // 0..15 -> micro col group
    const int ty = tid >> 4;   // 0..15 -> micro row group

    // B loader: 64 consecutive lanes load 64 consecutive floats (coalesced)
    const int bn  = tid & 63;
    const int bk4 = (tid >> 6) * 4;

    float acc[4][4] = {{0.f}};

    for (int kb = 0; kb < K; kb += TILE_K) {
        #pragma unroll
        for (int r = 0; r < 4; ++r) {
            As[ty * 4 + r][tx] =
                A[(size_t)(block_row + ty * 4 + r) * lda + kb + tx];
        }
        #pragma unroll
        for (int r = 0; r < 4; ++r) {
            Bs[bk4 + r][bn] =
                B[(size_t)(kb + bk4 + r) * ldb + block_col + bn];
        }
        __syncthreads();

        #pragma unroll
        for (int kk = 0; kk < TILE_K; ++kk) {
            float a0 = As[ty * 4 + 0][kk];
            float a1 = As[ty * 4 + 1][kk];
            float a2 = As[ty * 4 + 2][kk];
            float a3 = As[ty * 4 + 3][kk];
            float b0 = Bs[kk][tx * 4 + 0];
            float b1 = Bs[kk][tx * 4 + 1];
            float b2 = Bs[kk][tx * 4 + 2];
            float b3 = Bs[kk][tx * 4 + 3];
            acc[0][0] += a0 * b0; acc[0][1] += a0 * b1; acc[0][2] += a0 * b2; acc[0][3] += a0 * b3;
            acc[1][0] += a1 * b0; acc[1][1] += a1 * b1; acc[1][2] += a1 * b2; acc[1][3] += a1 * b3;
            acc[2][0] += a2 * b0; acc[2][1] += a2 * b1; acc[2][2] += a2 * b2; acc[2][3] += a2 * b3;
            acc[3][0] += a3 * b0; acc[3][1] += a3 * b1; acc[3][2] += a3 * b2; acc[3][3] += a3 * b3;
        }
        __syncthreads();
    }

    #pragma unroll
    for (int i = 0; i < 4; ++i) {
        const int row = block_row + ty * 4 + i;
        #pragma unroll
        for (int j = 0; j < 4; ++j) {
            const int col = block_col + tx * 4 + j;
            float v = acc[i][j];
            size_t cidx = (size_t)row * ldc + col;
            if (mode == MODE_TANH) {
                v = tanhf(v + bias[col]);
                C[cidx] = v;
            } else if (mode == MODE_DA2) {
                float t = tanhf(v + bias[col]);
                C[cidx] = aux[col] * (1.f - t * t);
            } else if (mode == MODE_DA1) {
                float h = aux[cidx];
                C[cidx] = v * (1.f - h * h);
            } else { // MODE_UPD
                C[cidx] += coef * v;
            }
        }
    }
}

__global__ __launch_bounds__(256)
void init_zp_kernel(const float* __restrict__ z, float* __restrict__ zp)
{
    size_t i = (size_t)blockIdx.x * 256 + threadIdx.x;   // over BATCH*ZDIM
    int c = (int)(i & (ZDIM - 1));
    size_t m = i >> 10;
    zp[i] = (c < DIM) ? z[m * DIM + c] : 0.f;
}

__global__ __launch_bounds__(256)
void transpose_kernel(const float* __restrict__ src, float* __restrict__ dst,
                      int R, int Cn)
{
    int i = blockIdx.x * 256 + threadIdx.x;   // over R*Cn
    if (i < R * Cn) {
        int r = i / Cn;
        int c = i - r * Cn;
        dst[(size_t)c * R + r] = src[i];
    }
}

__global__ __launch_bounds__(256)
void extract_q_kernel(const float* __restrict__ zp, float* __restrict__ out)
{
    size_t i = (size_t)blockIdx.x * 256 + threadIdx.x;   // over BATCH*DIM
    int c = (int)(i & (DIM - 1));
    size_t m = i >> 9;
    out[i] = zp[m * ZDIM + c];
}

extern "C" void kernel_launch(void* const* d_in, const int* in_sizes, int n_in,
                              void* d_out, int out_size, void* d_ws, size_t ws_size,
                              hipStream_t stream)
{
    const float* z  = (const float*)d_in[0];
    const float* W1 = (const float*)d_in[1];
    const float* b1 = (const float*)d_in[2];
    const float* W2 = (const float*)d_in[3];
    const float* b2 = (const float*)d_in[4];
    const float* W3 = (const float*)d_in[5];
    // b3 (d_in[6]) does not affect the gradient
    float* out = (float*)d_out;

    float* ws  = (float*)d_ws;
    float* zp  = ws;                                  // BATCH*ZDIM
    float* h1  = zp  + (size_t)BATCH * ZDIM;          // BATCH*HID
    float* da2 = h1  + (size_t)BATCH * HID;           // BATCH*HID
    float* da1 = da2 + (size_t)BATCH * HID;           // BATCH*HID
    float* W1T = da1 + (size_t)BATCH * HID;           // HID*ZDIM   (W1T[n][k] = W1[k][n])
    float* W2T = W1T + (size_t)HID * ZDIM;            // HID*HID    (W2T[n][k] = W2[k][n])

    // init zp = [z | 0]
    init_zp_kernel<<<(BATCH * ZDIM) / 256, 256, 0, stream>>>(z, zp);
    // transposes (cheap, done every call for graph-capture safety)
    transpose_kernel<<<(ZDIM * HID + 255) / 256, 256, 0, stream>>>(W1, W1T, ZDIM, HID);
    transpose_kernel<<<(HID * HID + 255) / 256, 256, 0, stream>>>(W2, W2T, HID, HID);

    const dim3 block(256);
    const dim3 grid_h(HID / TILE_N, BATCH / TILE_M);   // (4, 256)
    const dim3 grid_u(DIM / TILE_N, BATCH / TILE_M);   // (8, 256)

    for (int step = 0; step < 3; ++step) {
        for (int call = 0; call < 3; ++call) {
            // call 0,2: p -= 0.5*dt * g[:, :DIM]  -> grad rows 0..511 of W1, write zp cols 512..1023
            // call 1:   q += dt * g[:, DIM:]      -> grad rows 512..1023,   write zp cols 0..511
            const int src_off = (call == 1) ? DIM : 0;
            const int dst_off = (call == 1) ? 0 : DIM;
            const float coef  = (call == 1) ? DT : -0.5f * DT;

            // K1: h1 = tanh(zp @ W1 + b1)
            gemm_fused<<<grid_h, block, 0, stream>>>(
                zp, ZDIM, W1, HID, b1, nullptr, h1, HID, ZDIM, MODE_TANH, 0.f);
            // K2: da2 = W3 * (1 - tanh(h1 @ W2 + b2)^2)
            gemm_fused<<<grid_h, block, 0, stream>>>(
                h1, HID, W2, HID, b2, W3, da2, HID, HID, MODE_DA2, 0.f);
            // K3: da1 = (da2 @ W2^T) * (1 - h1^2)
            gemm_fused<<<grid_h, block, 0, stream>>>(
                da2, HID, W2T, HID, nullptr, h1, da1, HID, HID, MODE_DA1, 0.f);
            // K4: zp[:, dst_off:dst_off+512] += coef * (da1 @ W1T[:, src_off:src_off+512])
            gemm_fused<<<grid_u, block, 0, stream>>>(
                da1, HID, W1T + src_off, ZDIM, nullptr, nullptr,
                zp + dst_off, ZDIM, HID, MODE_UPD, coef);
        }
    }

    extract_q_kernel<<<(BATCH * DIM) / 256, 256, 0, stream>>>(zp, out);
}

// Round 2
// 2195.292 us; speedup vs baseline: 1.5433x; 1.5433x over previous
//
#include <hip/hip_runtime.h>
#include <math.h>

#define DT 0.1f

typedef __attribute__((ext_vector_type(8))) short short8;
typedef __attribute__((ext_vector_type(4))) float f32x4;

#define LDZ 1032   // 1024 + 8 pad (bf16 elems): row stride 2064B -> 4-bank step, 2-way (free)
#define LDH 264    // 256 + 8 pad

__device__ __forceinline__ short f2bf(float x) {
    unsigned int u = __float_as_uint(x);
    unsigned int r = (u + 0x7fffu + ((u >> 16) & 1u)) >> 16;  // RNE
    return (short)r;
}
__device__ __forceinline__ float bf2f(short s) {
    return __uint_as_float(((unsigned int)(unsigned short)s) << 16);
}
__device__ __forceinline__ float tanh_fast(float x) {
    float e = __expf(2.f * x);
    return 1.f - 2.f / (e + 1.f);   // handles +/-inf correctly
}

// ---- weight packing into MFMA B-fragment order ----
// out[((nt*KT + kt)*64 + lane)*8 + j] = B[kt*32 + (lane>>4)*8 + j][nt*16 + (lane&15)]
__global__ __launch_bounds__(256)
void pack_direct(const float* __restrict__ W, short* __restrict__ out, int K, int N)
{
    int idx = blockIdx.x * 256 + threadIdx.x;
    if (idx >= K * N) return;
    int j = idx & 7;
    int lane = (idx >> 3) & 63;
    int rest = idx >> 9;
    int KT = K >> 5;
    int kt = rest % KT;
    int nt = rest / KT;
    int k = kt * 32 + (lane >> 4) * 8 + j;
    int n = nt * 16 + (lane & 15);
    out[idx] = f2bf(W[k * N + n]);           // B = W (row-major K x N)
}
__global__ __launch_bounds__(256)
void pack_trans(const float* __restrict__ W, short* __restrict__ out, int K, int N)
{
    int idx = blockIdx.x * 256 + threadIdx.x;
    if (idx >= K * N) return;
    int j = idx & 7;
    int lane = (idx >> 3) & 63;
    int rest = idx >> 9;
    int KT = K >> 5;
    int kt = rest % KT;
    int nt = rest / KT;
    int k = kt * 32 + (lane >> 4) * 8 + j;
    int n = nt * 16 + (lane & 15);
    out[idx] = f2bf(W[n * K + k]);           // B = W^T (W row-major N x K)
}

// Compute 4 adjacent 16x16 n-tiles over all KT k-tiles.
// a0: LDS A base already offset by (lane&15)*ld + (lane>>4)*8; k-tile stride = 32 elems.
// Bp: packed fragments, frag index = (nt*KT + kt)*64 + lane.
template<int KT>
__device__ __forceinline__ void mma4(const short* a0,
                                     const short8* __restrict__ Bp,
                                     int nt0, int lane, f32x4* acc)
{
    constexpr int NG = KT / 4;
    short8 A[2][4];
    short8 B[2][4][4];
#pragma unroll
    for (int k = 0; k < 4; ++k) {
        A[0][k] = *(const short8*)(a0 + k * 32);
#pragma unroll
        for (int n = 0; n < 4; ++n)
            B[0][n][k] = Bp[((nt0 + n) * KT + k) * 64 + lane];
    }
#pragma unroll
    for (int g = 0; g < NG; ++g) {
        const int cur = g & 1, nxt = cur ^ 1;
        if (g + 1 < NG) {
#pragma unroll
            for (int k = 0; k < 4; ++k) {
                const int kk = (g + 1) * 4 + k;
                A[nxt][k] = *(const short8*)(a0 + kk * 32);
#pragma unroll
                for (int n = 0; n < 4; ++n)
                    B[nxt][n][k] = Bp[((nt0 + n) * KT + kk) * 64 + lane];
            }
        }
#pragma unroll
        for (int k = 0; k < 4; ++k) {
#pragma unroll
            for (int n = 0; n < 4; ++n)
                acc[n] = __builtin_amdgcn_mfma_f32_16x16x32_bf16(A[cur][k], B[cur][n][k], acc[n], 0, 0, 0);
        }
    }
}

// One block = 16 batch rows, 4 waves (wave w covers n-tiles [4w, 4w+4)).
// All 3 leapfrog steps x 3 gradH evals stay on-chip.
__global__ __launch_bounds__(256, 2)
void fused_leapfrog(const float* __restrict__ z,
                    const float* __restrict__ b1,
                    const float* __restrict__ b2,
                    const float* __restrict__ W3,
                    const short* __restrict__ PB1,
                    const short* __restrict__ PB2,
                    const short* __restrict__ PB2T,
                    const short* __restrict__ PB1T,
                    float* __restrict__ out)
{
    __shared__ short zp_s[16 * LDZ];
    __shared__ short h1_s[16 * LDH];
    __shared__ short da_s[16 * LDH];
    __shared__ float b1_s[256], b2_s[256], w3_s[256];

    const int tid  = threadIdx.x;
    const int lane = tid & 63;
    const int cg   = tid >> 6;        // wave 0..3 -> column group
    const int lrow = lane & 15;
    const int quad = lane >> 4;
    const size_t rowbase = (size_t)blockIdx.x * 16;

    if (tid < 256) {
        b1_s[tid] = b1[tid];
        b2_s[tid] = b2[tid];
        w3_s[tid] = W3[tid];
    }
    for (int i = tid; i < 16 * 512; i += 256) {
        int r = i >> 9, c = i & 511;
        zp_s[r * LDZ + c]       = f2bf(z[(rowbase + r) * 512 + c]);
        zp_s[r * LDZ + 512 + c] = 0;   // p = 0
    }
    __syncthreads();

    const short* zp_a = zp_s + lrow * LDZ + quad * 8;
    const short* h1_a = h1_s + lrow * LDH + quad * 8;
    const short* da_a = da_s + lrow * LDH + quad * 8;

    const f32x4 zf = {0.f, 0.f, 0.f, 0.f};

    for (int it = 0; it < 9; ++it) {
        const int call    = it % 3;
        const bool isq    = (call == 1);
        const int src_nt  = isq ? 32 : 0;     // W1T n-tile base: dH/dq -> [0,512), dH/dp -> [512,1024)
        const int dst_off = isq ? 0 : 512;    // update q or p half of zp
        const float coef  = isq ? DT : (-0.5f * DT);

        // K1: h1 = tanh(zp @ W1 + b1)           [16x1024 @ 1024x256]
        {
            f32x4 acc[4] = {zf, zf, zf, zf};
            mma4<32>(zp_a, (const short8*)PB1, cg * 4, lane, acc);
#pragma unroll
            for (int n = 0; n < 4; ++n) {
                const int col = (cg * 4 + n) * 16 + lrow;
                const float bb = b1_s[col];
#pragma unroll
                for (int r = 0; r < 4; ++r) {
                    const int row = quad * 4 + r;
                    h1_s[row * LDH + col] = f2bf(tanh_fast(acc[n][r] + bb));
                }
            }
        }
        __syncthreads();

        // K2: da2 = W3 * (1 - tanh(h1 @ W2 + b2)^2)
        {
            f32x4 acc[4] = {zf, zf, zf, zf};
            mma4<8>(h1_a, (const short8*)PB2, cg * 4, lane, acc);
#pragma unroll
            for (int n = 0; n < 4; ++n) {
                const int col = (cg * 4 + n) * 16 + lrow;
                const float bb = b2_s[col];
                const float w3c = w3_s[col];
#pragma unroll
                for (int r = 0; r < 4; ++r) {
                    const int row = quad * 4 + r;
                    float t = tanh_fast(acc[n][r] + bb);
                    da_s[row * LDH + col] = f2bf(w3c * (1.f - t * t));
                }
            }
        }
        __syncthreads();

        // K3: da1 = (da2 @ W2^T) * (1 - h1^2)   (in-place on da_s, barrier-protected)
        {
            f32x4 acc[4] = {zf, zf, zf, zf};
            mma4<8>(da_a, (const short8*)PB2T, cg * 4, lane, acc);
            __syncthreads();   // all waves done READING da2 before overwrite
#pragma unroll
            for (int n = 0; n < 4; ++n) {
                const int col = (cg * 4 + n) * 16 + lrow;
#pragma unroll
                for (int r = 0; r < 4; ++r) {
                    const int row = quad * 4 + r;
                    float h = bf2f(h1_s[row * LDH + col]);
                    da_s[row * LDH + col] = f2bf(acc[n][r] * (1.f - h * h));
                }
            }
        }
        __syncthreads();

        // K4: zp[:, dst_off:dst_off+512] += coef * (da1 @ W1T[:, src:src+512])
#pragma unroll
        for (int p = 0; p < 2; ++p) {
            f32x4 acc[4] = {zf, zf, zf, zf};
            mma4<8>(da_a, (const short8*)PB1T, src_nt + cg * 8 + p * 4, lane, acc);
#pragma unroll
            for (int n = 0; n < 4; ++n) {
                const int cz = dst_off + (cg * 8 + p * 4 + n) * 16 + lrow;
#pragma unroll
                for (int r = 0; r < 4; ++r) {
                    const int row = quad * 4 + r;
                    const int ix = row * LDZ + cz;
                    zp_s[ix] = f2bf(bf2f(zp_s[ix]) + coef * acc[n][r]);
                }
            }
        }
        __syncthreads();
    }

    for (int i = tid; i < 16 * 512; i += 256) {
        int r = i >> 9, c = i & 511;
        out[(rowbase + r) * 512 + c] = bf2f(zp_s[r * LDZ + c]);
    }
}

extern "C" void kernel_launch(void* const* d_in, const int* in_sizes, int n_in,
                              void* d_out, int out_size, void* d_ws, size_t ws_size,
                              hipStream_t stream)
{
    const float* z  = (const float*)d_in[0];
    const float* W1 = (const float*)d_in[1];   // 1024 x 256
    const float* b1 = (const float*)d_in[2];
    const float* W2 = (const float*)d_in[3];   // 256 x 256
    const float* b2 = (const float*)d_in[4];
    const float* W3 = (const float*)d_in[5];   // 256 x 1
    float* out = (float*)d_out;

    short* PB1  = (short*)d_ws;        // K=1024,N=256 : 262144 bf16
    short* PB2  = PB1  + 262144;       // K=256, N=256 :  65536
    short* PB2T = PB2  + 65536;        // K=256, N=256 :  65536
    short* PB1T = PB2T + 65536;        // K=256, N=1024: 262144

    pack_direct<<<1024, 256, 0, stream>>>(W1, PB1, 1024, 256);
    pack_direct<<<256,  256, 0, stream>>>(W2, PB2, 256, 256);
    pack_trans <<<256,  256, 0, stream>>>(W2, PB2T, 256, 256);
    pack_trans <<<1024, 256, 0, stream>>>(W1, PB1T, 256, 1024);

    fused_leapfrog<<<1024, 256, 0, stream>>>(z, b1, b2, W3, PB1, PB2, PB2T, PB1T, out);
}

// Round 3
// 631.647 us; speedup vs baseline: 5.3638x; 3.4755x over previous
//
#include <hip/hip_runtime.h>
#include <math.h>

#define DT 0.1f
#define BM 64
#define BN 128
#define BK 64

typedef __attribute__((ext_vector_type(8))) short short8;
typedef __attribute__((ext_vector_type(4))) short short4v;
typedef __attribute__((ext_vector_type(4))) float f32x4;

__device__ __forceinline__ short f2bf(float x) {
    unsigned int u = __float_as_uint(x);
    unsigned int r = (u + 0x7fffu + ((u >> 16) & 1u)) >> 16;  // RNE
    return (short)r;
}
__device__ __forceinline__ float bf2f(short s) {
    return __uint_as_float(((unsigned int)(unsigned short)s) << 16);
}
__device__ __forceinline__ float tanh_fast(float x) {
    float e = __expf(2.f * x);
    return 1.f - 2.f / (e + 1.f);
}
__device__ __forceinline__ void async_cp16(const void* gp, void* lp) {
    __builtin_amdgcn_global_load_lds(
        (const __attribute__((address_space(1))) void*)gp,
        (__attribute__((address_space(3))) void*)lp, 16, 0, 0);
}

// ---- weight packing into MFMA B-fragment order (verified in R2) ----
// out[((nt*KT + kt)*64 + lane)*8 + j] = B[kt*32 + (lane>>4)*8 + j][nt*16 + (lane&15)]
__global__ __launch_bounds__(256)
void pack_direct(const float* __restrict__ W, short* __restrict__ out, int K, int N)
{
    int idx = blockIdx.x * 256 + threadIdx.x;
    if (idx >= K * N) return;
    int j = idx & 7;
    int lane = (idx >> 3) & 63;
    int rest = idx >> 9;
    int KT = K >> 5;
    int kt = rest % KT;
    int nt = rest / KT;
    int k = kt * 32 + (lane >> 4) * 8 + j;
    int n = nt * 16 + (lane & 15);
    out[idx] = f2bf(W[k * N + n]);
}
__global__ __launch_bounds__(256)
void pack_trans(const float* __restrict__ W, short* __restrict__ out, int K, int N)
{
    int idx = blockIdx.x * 256 + threadIdx.x;
    if (idx >= K * N) return;
    int j = idx & 7;
    int lane = (idx >> 3) & 63;
    int rest = idx >> 9;
    int KT = K >> 5;
    int kt = rest % KT;
    int nt = rest / KT;
    int k = kt * 32 + (lane >> 4) * 8 + j;
    int n = nt * 16 + (lane & 15);
    out[idx] = f2bf(W[n * K + k]);
}

// Stage one BK=64 slab of A (BM x 64, XOR-swizzled chunks) and B (8 n-tile
// strips x 2 k-tiles of packed fragments) into LDS via async global->LDS.
__device__ __forceinline__ void stage(const short* A, int lda, int row0, int kb,
                                      const short* Bp, int KT, int n0t,
                                      char* Abuf, char* Bbuf, int tid)
{
    // A: BM*BK bf16 = 8 KB = 2 rounds x 256 lanes x 16B
#pragma unroll
    for (int j = 0; j < 2; ++j) {
        int lin = j * 256 + tid;
        int row = lin >> 3, s = lin & 7;
        int g = (s + row) & 7;                       // XOR-ish swizzle (global side)
        const short* gp = A + (size_t)(row0 + row) * lda + kb * 64 + g * 8;
        async_cp16(gp, Abuf + lin * 16);
    }
    // B: 8 strips x 2048B = 16 KB = 4 rounds
#pragma unroll
    for (int j = 0; j < 4; ++j) {
        int lin = j * 256 + tid;
        int strip = lin >> 7, within = lin & 127;    // within: 16B units inside strip
        const short* gp = Bp + ((size_t)(n0t + strip) * KT + kb * 2) * 512 + within * 8;
        async_cp16(gp, Bbuf + lin * 16);
    }
}

// MFMA on one staged slab: wave (mr,nc) covers 32 rows x 64 cols.
__device__ __forceinline__ void compute(const char* Abuf, const char* Bbuf,
                                        int mr, int nc, int lane, f32x4 acc[2][4])
{
    const int lrow = lane & 15, quad = lane >> 4;
#pragma unroll
    for (int ktl = 0; ktl < 2; ++ktl) {
        short8 a[2], b[4];
#pragma unroll
        for (int ai = 0; ai < 2; ++ai) {
            int r = (mr * 2 + ai) * 16 + lrow;
            int g = ktl * 4 + quad;
            int s = (g - r) & 7;                     // undo swizzle
            a[ai] = *(const short8*)(Abuf + r * 128 + s * 16);
        }
#pragma unroll
        for (int bi = 0; bi < 4; ++bi) {
            int ntl = nc * 4 + bi;
            b[bi] = *(const short8*)(Bbuf + ((ntl * 2 + ktl) * 64 + lane) * 16);
        }
#pragma unroll
        for (int ai = 0; ai < 2; ++ai)
#pragma unroll
            for (int bi = 0; bi < 4; ++bi)
                acc[ai][bi] = __builtin_amdgcn_mfma_f32_16x16x32_bf16(a[ai], b[bi], acc[ai][bi], 0, 0, 0);
    }
}

// modes: 0 C=tanh(acc+bias); 1 C=w3*(1-tanh(acc+bias)^2);
//        2 C=acc*(1-aux^2);  3 C += coef*acc (rmw, coef folded in phase1)
__global__ __launch_bounds__(256, 3)
void gemm_mfma(const short* __restrict__ A, int lda,
               const short* __restrict__ Bp, int KT,
               const float* __restrict__ bias, const float* __restrict__ w3,
               const short* __restrict__ aux, int ldaux,
               short* __restrict__ C, int ldc,
               int mode, float coef)
{
    __shared__ char Ab[2][8192];
    __shared__ char Bb[2][16384];

    const int tid = threadIdx.x;
    const int lane = tid & 63, wid = tid >> 6;
    const int mr = wid >> 1, nc = wid & 1;
    const int row0 = blockIdx.y * BM;
    const int n0 = blockIdx.x * BN;
    const int n0t = n0 >> 4;

    const f32x4 zf = {0.f, 0.f, 0.f, 0.f};
    f32x4 acc[2][4] = {{zf, zf, zf, zf}, {zf, zf, zf, zf}};

    const int NKB = KT >> 1;   // always even (16 or 4) -> last compute uses buf 1
    stage(A, lda, row0, 0, Bp, KT, n0t, Ab[0], Bb[0], tid);
    int buf = 0;
    for (int kb = 0; kb < NKB; ++kb) {
        __syncthreads();       // compiler drains vmcnt(0) before s_barrier
        if (kb + 1 < NKB)
            stage(A, lda, row0, kb + 1, Bp, KT, n0t, Ab[buf ^ 1], Bb[buf ^ 1], tid);
        compute(Ab[buf], Bb[buf], mr, nc, lane, acc);
        buf ^= 1;
    }

    // ---- phase 1: col-dependent epilogue on acc -> bf16 C-tile in LDS ----
    short* Ct = (short*)&Bb[0][0];   // 64 x 128 bf16 = 16 KB (buf0 free: last compute read buf1)
    const int lrow = lane & 15, quad = lane >> 4;
#pragma unroll
    for (int bi = 0; bi < 4; ++bi) {
        const int ntl = nc * 4 + bi;
        const int gcol = n0 + ntl * 16 + lrow;
        float bb = 0.f, w3c = 0.f;
        if (mode <= 1) bb = bias[gcol];
        if (mode == 1) w3c = w3[gcol];
#pragma unroll
        for (int ai = 0; ai < 2; ++ai) {
            const int crow = (mr * 2 + ai) * 16 + quad * 4;
#pragma unroll
            for (int r = 0; r < 4; ++r) {
                float v = acc[ai][bi][r];
                if (mode == 0)      v = tanh_fast(v + bb);
                else if (mode == 1) { float t = tanh_fast(v + bb); v = w3c * (1.f - t * t); }
                else if (mode == 3) v = coef * v;
                Ct[(crow + r) * BN + ntl * 16 + lrow] = f2bf(v);
            }
        }
    }
    __syncthreads();

    // ---- phase 2: coalesced 16B copy-out with optional mask / rmw ----
#pragma unroll
    for (int j = 0; j < 4; ++j) {
        int lin = j * 256 + tid;
        int row = lin >> 4, chunk = lin & 15;
        size_t goff = (size_t)(row0 + row) * ldc + n0 + chunk * 8;
        short8 v = *(const short8*)(Ct + lin * 8);
        if (mode == 2) {
            short8 h = *(const short8*)(aux + (size_t)(row0 + row) * ldaux + n0 + chunk * 8);
#pragma unroll
            for (int e = 0; e < 8; ++e) {
                float hh = bf2f(h[e]);
                v[e] = f2bf(bf2f(v[e]) * (1.f - hh * hh));
            }
        } else if (mode == 3) {
            short8 zv = *(const short8*)(C + goff);
#pragma unroll
            for (int e = 0; e < 8; ++e)
                v[e] = f2bf(bf2f(zv[e]) + bf2f(v[e]));
        }
        *(short8*)(C + goff) = v;
    }
}

__global__ __launch_bounds__(256)
void init_zp(const float* __restrict__ z, short* __restrict__ zp)
{
    size_t i = (size_t)blockIdx.x * 256 + threadIdx.x;   // quads over 16384x1024
    int qc = (int)(i & 255);
    size_t r = i >> 8;
    short4v o;
    if (qc < 128) {
        const float4* z4 = (const float4*)z;
        float4 v = z4[r * 128 + qc];
        o.x = f2bf(v.x); o.y = f2bf(v.y); o.z = f2bf(v.z); o.w = f2bf(v.w);
    } else {
        o.x = 0; o.y = 0; o.z = 0; o.w = 0;
    }
    ((short4v*)zp)[i] = o;
}

__global__ __launch_bounds__(256)
void extract_q(const short* __restrict__ zp, float* __restrict__ out)
{
    size_t i = (size_t)blockIdx.x * 256 + threadIdx.x;   // quads over 16384x512
    int qc = (int)(i & 127);
    size_t r = i >> 7;
    short4v v = ((const short4v*)zp)[r * 256 + qc];
    float4 o;
    o.x = bf2f(v.x); o.y = bf2f(v.y); o.z = bf2f(v.z); o.w = bf2f(v.w);
    ((float4*)out)[i] = o;
}

extern "C" void kernel_launch(void* const* d_in, const int* in_sizes, int n_in,
                              void* d_out, int out_size, void* d_ws, size_t ws_size,
                              hipStream_t stream)
{
    const float* z  = (const float*)d_in[0];
    const float* W1 = (const float*)d_in[1];   // 1024 x 256
    const float* b1 = (const float*)d_in[2];
    const float* W2 = (const float*)d_in[3];   // 256 x 256
    const float* b2 = (const float*)d_in[4];
    const float* W3 = (const float*)d_in[5];   // 256 x 1
    float* out = (float*)d_out;

    short* zp   = (short*)d_ws;                        // 16384x1024
    short* h1   = zp   + (size_t)16384 * 1024;         // 16384x256
    short* da2  = h1   + (size_t)16384 * 256;
    short* da1  = da2  + (size_t)16384 * 256;
    short* PB1  = da1  + (size_t)16384 * 256;          // K=1024,N=256 (KT=32)
    short* PB2  = PB1  + 262144;                       // K=256,N=256  (KT=8)
    short* PB2T = PB2  + 65536;
    short* PB1T = PB2T + 65536;                        // K=256,N=1024 (KT=8)

    pack_direct<<<1024, 256, 0, stream>>>(W1, PB1, 1024, 256);
    pack_direct<<<256,  256, 0, stream>>>(W2, PB2, 256, 256);
    pack_trans <<<256,  256, 0, stream>>>(W2, PB2T, 256, 256);
    pack_trans <<<1024, 256, 0, stream>>>(W1, PB1T, 256, 1024);
    init_zp<<<16384, 256, 0, stream>>>(z, zp);

    const dim3 blk(256);
    const dim3 g2(2, 256);   // N=256 GEMMs
    const dim3 g4(4, 256);   // N=512 GEMM (K4)

    for (int it = 0; it < 9; ++it) {
        const int call = it % 3;
        const bool isq = (call == 1);
        const int src_nt  = isq ? 32 : 0;       // g cols: dH/dp -> [512,1024) is nt 32..63
        const int dst_off = isq ? 0 : 512;
        const float coef  = isq ? DT : (-0.5f * DT);

        // K1: h1 = tanh(zp @ W1 + b1)
        gemm_mfma<<<g2, blk, 0, stream>>>(zp, 1024, PB1, 32, b1, b1, h1, 256,
                                          h1, 256, 0, 0.f);
        // K2: da2 = W3 * (1 - tanh(h1 @ W2 + b2)^2)
        gemm_mfma<<<g2, blk, 0, stream>>>(h1, 256, PB2, 8, b2, W3, h1, 256,
                                          da2, 256, 1, 0.f);
        // K3: da1 = (da2 @ W2^T) * (1 - h1^2)
        gemm_mfma<<<g2, blk, 0, stream>>>(da2, 256, PB2T, 8, b1, b1, h1, 256,
                                          da1, 256, 2, 0.f);
        // K4: zp[:, dst:dst+512] += coef * (da1 @ W1T[:, src:src+512])
        gemm_mfma<<<g4, blk, 0, stream>>>(da1, 256, PB1T + (size_t)src_nt * 8 * 512, 8,
                                          b1, b1, zp, 1024,
                                          zp + dst_off, 1024, 3, coef);
    }

    extract_q<<<8192, 256, 0, stream>>>(zp, out);
}